// Round 1
// baseline (200.088 us; speedup 1.0000x reference)
//
#include <hip/hip_runtime.h>
#include <hip/hip_bf16.h>

// GAT: N=4096 nodes, IN_F=256, H=4 heads, D=64.
// K1 gat_prep : h = x@W (fp32), si/sj = h.a1/h.a2 (scaled by log2e), hT bf16 [H][D][N],
//               per-block sj-max partials.
// K2 gat_attn : flash-style masked softmax + PV via mfma_16x16x32_bf16.
//               m[i,h] = leaky(si + max_j sj) upper bound -> softmax is a pure sum -> j-splittable.
// K3 gat_reduce: out = sum_s acc / sum_s l.

typedef __bf16 bf16x8 __attribute__((ext_vector_type(8)));
typedef float floatx4 __attribute__((ext_vector_type(4)));

#define LOG2E 1.4426950408889634f
#define NN 4096

// ---------------- Kernel A: h = x@W + si/sj + hT(bf16) ----------------
// grid (64 i-tiles, 4 heads), 256 threads. Block computes h[i0:i0+64][hh*64:+64].
__global__ __launch_bounds__(256) void gat_prep(
    const float* __restrict__ x, const float* __restrict__ W,
    const float* __restrict__ a1, const float* __restrict__ a2,
    __bf16* __restrict__ hT, float* __restrict__ siT, float* __restrict__ sjT,
    float* __restrict__ sjm) {
  __shared__ float hl[64 * 68];   // 68-pad: 16B-aligned rows, conflict-free-ish
  __shared__ float sjb[64];
  const int t = threadIdx.x;
  const int it = blockIdx.x, hh = blockIdx.y;
  const int i0 = it * 64, c0 = hh * 64;
  const int tr = t >> 4, tc = t & 15;   // 16 row-groups x 16 col-groups, 4x4 micro-tile

  float acc[4][4] = {{0.f,0.f,0.f,0.f},{0.f,0.f,0.f,0.f},
                     {0.f,0.f,0.f,0.f},{0.f,0.f,0.f,0.f}};
  const float* xr = x + (size_t)(i0 + tr * 4) * 256;
  const float* wp = W + c0 + tc * 4;
  for (int k = 0; k < 256; k += 4) {
    float4 xv0 = *(const float4*)(xr + k);
    float4 xv1 = *(const float4*)(xr + 256 + k);
    float4 xv2 = *(const float4*)(xr + 512 + k);
    float4 xv3 = *(const float4*)(xr + 768 + k);
    float xs[4][4] = {{xv0.x, xv0.y, xv0.z, xv0.w},
                      {xv1.x, xv1.y, xv1.z, xv1.w},
                      {xv2.x, xv2.y, xv2.z, xv2.w},
                      {xv3.x, xv3.y, xv3.z, xv3.w}};
#pragma unroll
    for (int kk = 0; kk < 4; ++kk) {
      float4 wv = *(const float4*)(wp + (size_t)(k + kk) * 256);
#pragma unroll
      for (int i = 0; i < 4; ++i) {
        acc[i][0] = fmaf(xs[i][kk], wv.x, acc[i][0]);
        acc[i][1] = fmaf(xs[i][kk], wv.y, acc[i][1]);
        acc[i][2] = fmaf(xs[i][kk], wv.z, acc[i][2]);
        acc[i][3] = fmaf(xs[i][kk], wv.w, acc[i][3]);
      }
    }
  }

  // si/sj row dots (a1/a2 indexed by local d = tc*4+j), reduce over tc lanes.
  float4 a1v = *(const float4*)(a1 + tc * 4);
  float4 a2v = *(const float4*)(a2 + tc * 4);
#pragma unroll
  for (int i = 0; i < 4; ++i) {
    float s1 = acc[i][0]*a1v.x + acc[i][1]*a1v.y + acc[i][2]*a1v.z + acc[i][3]*a1v.w;
    float s2 = acc[i][0]*a2v.x + acc[i][1]*a2v.y + acc[i][2]*a2v.z + acc[i][3]*a2v.w;
#pragma unroll
    for (int off = 1; off < 16; off <<= 1) {
      s1 += __shfl_xor(s1, off);
      s2 += __shfl_xor(s2, off);
    }
    if (tc == 0) {
      int r = tr * 4 + i;
      siT[hh * NN + i0 + r] = s1 * LOG2E;   // store pre-scaled by log2(e)
      float v2 = s2 * LOG2E;
      sjT[hh * NN + i0 + r] = v2;
      sjb[r] = v2;
    }
    *(float4*)&hl[(tr * 4 + i) * 68 + tc * 4] =
        make_float4(acc[i][0], acc[i][1], acc[i][2], acc[i][3]);
  }
  __syncthreads();

  if (t < 64) {  // wave 0: block-level sj max partial
    float v = sjb[t];
#pragma unroll
    for (int off = 1; off < 64; off <<= 1) v = fmaxf(v, __shfl_xor(v, off));
    if (t == 0) sjm[it * 4 + hh] = v;
  }

  // transpose -> hT[hh][d][i0..i0+63] bf16 (16 i's per thread, 16B stores)
  const int d = t & 63, g = t >> 6;
  bf16x8 h0, h1;
#pragma unroll
  for (int ii = 0; ii < 8; ++ii) h0[ii] = (__bf16)hl[(g * 16 + ii) * 68 + d];
#pragma unroll
  for (int ii = 0; ii < 8; ++ii) h1[ii] = (__bf16)hl[(g * 16 + 8 + ii) * 68 + d];
  __bf16* hp = hT + (size_t)(hh * 64 + d) * NN + i0 + g * 16;
  *(bf16x8*)hp = h0;
  *(bf16x8*)(hp + 8) = h1;
}

// ---------------- Kernel B: masked softmax + PV (MFMA) ----------------
// grid (64 i-tiles, S j-splits), 256 threads = 4 waves, wave w = head w.
// Per wave: M=64 (4 subtiles of 16) x D=64 (4 subtiles of 16), K-loop over j in steps of 32.
__global__ __launch_bounds__(256, 2) void gat_attn(
    const int* __restrict__ adj, const __bf16* __restrict__ hT,
    const float* __restrict__ siT, const float* __restrict__ sjT,
    const float* __restrict__ sjm,
    float* __restrict__ accws, float* __restrict__ lws, int jper) {
  const int t = threadIdx.x;
  const int w = t >> 6, lane = t & 63, quad = lane >> 4, l16 = lane & 15;
  const int i0 = blockIdx.x * 64;
  const int s = blockIdx.y;
  const int jbeg = s * jper, jend = jbeg + jper;

  // global sj-max for this head (reduce 64 block-partials from gat_prep)
  float v = sjm[lane * 4 + w];
#pragma unroll
  for (int off = 1; off < 64; off <<= 1) v = fmaxf(v, __shfl_xor(v, off));

  // per-row constants in A-fragment row order (row = mt*16 + l16), scaled domain:
  // arg = max((si-m)+sj, (0.2si-m)+0.2sj); p = exp2(arg) [* adj mask]
  float sim[4], q2[4];
#pragma unroll
  for (int mt = 0; mt < 4; ++mt) {
    float si = siT[w * NN + i0 + mt * 16 + l16];
    float tt = si + v;
    float m = fmaxf(tt, 0.2f * tt);   // leaky is monotone -> valid upper bound on row max
    sim[mt] = si - m;
    q2[mt] = 0.2f * si - m;
  }

  floatx4 zv = {0.f, 0.f, 0.f, 0.f};
  floatx4 acc[4][4];
#pragma unroll
  for (int mt = 0; mt < 4; ++mt)
#pragma unroll
    for (int nt = 0; nt < 4; ++nt) acc[mt][nt] = zv;
  float lp[4] = {0.f, 0.f, 0.f, 0.f};

  const __bf16* hTw = hT + (size_t)w * 64 * NN;
  const float* sjw = sjT + w * NN;

  for (int j0 = jbeg; j0 < jend; j0 += 32) {
    // B-fragments: hT[w][nt*16+l16][j0+quad*8 ..+7], contiguous 16B
    bf16x8 bfr[4];
#pragma unroll
    for (int nt = 0; nt < 4; ++nt)
      bfr[nt] = *(const bf16x8*)(hTw + (size_t)(nt * 16 + l16) * NN + j0 + quad * 8);

    float4 sa = *(const float4*)(sjw + j0 + quad * 8);
    float4 sb = *(const float4*)(sjw + j0 + quad * 8 + 4);
    float sj[8] = {sa.x, sa.y, sa.z, sa.w, sb.x, sb.y, sb.z, sb.w};
    float sj2[8];
#pragma unroll
    for (int jj = 0; jj < 8; ++jj) sj2[jj] = 0.2f * sj[jj];

    bf16x8 afr[4];
#pragma unroll
    for (int mt = 0; mt < 4; ++mt) {
      const int* ar = adj + (size_t)(i0 + mt * 16 + l16) * NN + j0 + quad * 8;
      int4 am0 = *(const int4*)ar;
      int4 am1 = *(const int4*)(ar + 4);
      int am[8] = {am0.x, am0.y, am0.z, am0.w, am1.x, am1.y, am1.z, am1.w};
      bf16x8 af;
      float lacc = 0.f;
#pragma unroll
      for (int jj = 0; jj < 8; ++jj) {
        float t1 = sim[mt] + sj[jj];
        float t2 = q2[mt] + sj2[jj];
        float p = __builtin_amdgcn_exp2f(fmaxf(t1, t2));
        p = (am[jj] != 0) ? p : 0.f;
        lacc += p;
        af[jj] = (__bf16)p;
      }
      lp[mt] += lacc;
      afr[mt] = af;
    }
#pragma unroll
    for (int mt = 0; mt < 4; ++mt)
#pragma unroll
      for (int nt = 0; nt < 4; ++nt)
        acc[mt][nt] = __builtin_amdgcn_mfma_f32_16x16x32_bf16(afr[mt], bfr[nt],
                                                              acc[mt][nt], 0, 0, 0);
  }

  // l row sums: combine the 4 quads (same A-row l16)
#pragma unroll
  for (int mt = 0; mt < 4; ++mt) {
    lp[mt] += __shfl_xor(lp[mt], 16);
    lp[mt] += __shfl_xor(lp[mt], 32);
  }
  float* accs = accws + (size_t)s * NN * 256;
  float* lss = lws + (size_t)s * NN * 4;
  if (quad == 0) {
#pragma unroll
    for (int mt = 0; mt < 4; ++mt)
      lss[(i0 + mt * 16 + l16) * 4 + w] = lp[mt];
  }
  // C layout: row = mt*16 + quad*4 + reg, col = nt*16 + l16
#pragma unroll
  for (int mt = 0; mt < 4; ++mt)
#pragma unroll
    for (int reg = 0; reg < 4; ++reg) {
      int row = mt * 16 + quad * 4 + reg;
      float* op = accs + (size_t)(i0 + row) * 256 + w * 64;
#pragma unroll
      for (int nt = 0; nt < 4; ++nt)
        op[nt * 16 + l16] = acc[mt][nt][reg];
    }
}

// ---------------- Kernel C: combine splits + normalize ----------------
__global__ __launch_bounds__(256) void gat_reduce(
    const float* __restrict__ accws, const float* __restrict__ lws,
    float* __restrict__ out, int S) {
  const int e = blockIdx.x * 256 + threadIdx.x;   // e = i*256 + h*64 + d
  const int i = e >> 8;
  const int h = (e & 255) >> 6;
  float a = 0.f, l = 0.f;
  for (int s = 0; s < S; ++s) {
    a += accws[(size_t)s * (NN * 256) + e];
    l += lws[(size_t)s * (NN * 4) + i * 4 + h];
  }
  out[e] = a / l;
}

extern "C" void kernel_launch(void* const* d_in, const int* in_sizes, int n_in,
                              void* d_out, int out_size, void* d_ws, size_t ws_size,
                              hipStream_t stream) {
  const float* x  = (const float*)d_in[0];
  const int*   adj = (const int*)d_in[1];
  const float* W  = (const float*)d_in[2];
  const float* a1 = (const float*)d_in[3];
  const float* a2 = (const float*)d_in[4];
  float* out = (float*)d_out;
  char* ws = (char*)d_ws;

  // ws layout (bytes):
  //   hT   bf16 [4][64][4096]  @ 0        (2 MiB)
  //   siT  f32  [4][4096]      @ 2097152  (64 KiB)   (pre-scaled by log2e)
  //   sjT  f32  [4][4096]      @ 2162688  (64 KiB)
  //   sjm  f32  [64][4]        @ 2228224  (1 KiB)
  //   acc  f32  [S][4096][256] @ 2232320  (S * 4 MiB)
  //   l    f32  [S][4096][4]   after acc  (S * 64 KiB)
  __bf16* hT  = (__bf16*)ws;
  float* siT  = (float*)(ws + 2097152);
  float* sjT  = (float*)(ws + 2162688);
  float* sjm  = (float*)(ws + 2228224);
  float* accws = (float*)(ws + 2232320);

  size_t avail = ws_size > 2232320 ? ws_size - 2232320 : 0;
  int S = (int)(avail / 4259840);
  if (S >= 8) S = 8;
  else if (S >= 4) S = 4;
  else if (S >= 2) S = 2;
  else S = 1;
  float* lws = (float*)(ws + 2232320 + (size_t)S * 4194304);
  int jper = NN / S;

  gat_prep<<<dim3(64, 4), 256, 0, stream>>>(x, W, a1, a2, hT, siT, sjT, sjm);
  gat_attn<<<dim3(64, S), 256, 0, stream>>>(adj, hT, siT, sjT, sjm, accws, lws, jper);
  gat_reduce<<<4096, 256, 0, stream>>>(accws, lws, out, S);
}

// Round 2
// 197.237 us; speedup vs baseline: 1.0145x; 1.0145x over previous
//
#include <hip/hip_runtime.h>
#include <hip/hip_bf16.h>

// GAT: N=4096 nodes, IN_F=256, H=4 heads, D=64.
// K1 gat_prep : h = x@W (fp32), siT = <h,a1>*log2e, vT = exp2(<h,a2>*log2e),
//               v2T = exp2(0.2*...), hT bf16 [H][D][N], per-block sj-max partials.
// K2 gat_attn : masked softmax + PV via mfma_16x16x32_bf16.
//               m_i = max-bound over row -> pure-sum softmax -> j-splittable.
//               p_ij = max(u_i*v_j, u2_i*v2_j) : no transcendentals in hot loop.
// K3 gat_reduce: out = sum_s acc / sum_s l  (float4).

typedef __bf16 bf16x8 __attribute__((ext_vector_type(8)));
typedef float floatx4 __attribute__((ext_vector_type(4)));

#define LOG2E 1.4426950408889634f
#define NN 4096

// ---------------- Kernel A: h = x@W + per-row scalars + hT(bf16) ----------------
// grid (128 i-tiles of 32 rows, 4 heads), 256 threads.
__global__ __launch_bounds__(256) void gat_prep(
    const float* __restrict__ x, const float* __restrict__ W,
    const float* __restrict__ a1, const float* __restrict__ a2,
    __bf16* __restrict__ hT, float* __restrict__ siT, float* __restrict__ vT,
    float* __restrict__ v2T, float* __restrict__ sjm) {
  __shared__ float hl[32 * 68];
  __shared__ float sjb[32];
  const int t = threadIdx.x;
  const int it = blockIdx.x, hh = blockIdx.y;
  const int i0 = it * 32, c0 = hh * 64;
  const int tr = t >> 4, tc = t & 15;   // 16 row-groups x 16 col-groups, 2x4 micro-tile

  float acc[2][4] = {{0.f,0.f,0.f,0.f},{0.f,0.f,0.f,0.f}};
  const float* xr = x + (size_t)(i0 + tr * 2) * 256;
  const float* wp = W + c0 + tc * 4;
  for (int k = 0; k < 256; k += 4) {
    float4 xv0 = *(const float4*)(xr + k);
    float4 xv1 = *(const float4*)(xr + 256 + k);
    float xs[2][4] = {{xv0.x, xv0.y, xv0.z, xv0.w},
                      {xv1.x, xv1.y, xv1.z, xv1.w}};
#pragma unroll
    for (int kk = 0; kk < 4; ++kk) {
      float4 wv = *(const float4*)(wp + (size_t)(k + kk) * 256);
#pragma unroll
      for (int i = 0; i < 2; ++i) {
        acc[i][0] = fmaf(xs[i][kk], wv.x, acc[i][0]);
        acc[i][1] = fmaf(xs[i][kk], wv.y, acc[i][1]);
        acc[i][2] = fmaf(xs[i][kk], wv.z, acc[i][2]);
        acc[i][3] = fmaf(xs[i][kk], wv.w, acc[i][3]);
      }
    }
  }

  float4 a1v = *(const float4*)(a1 + tc * 4);
  float4 a2v = *(const float4*)(a2 + tc * 4);
#pragma unroll
  for (int i = 0; i < 2; ++i) {
    float s1 = acc[i][0]*a1v.x + acc[i][1]*a1v.y + acc[i][2]*a1v.z + acc[i][3]*a1v.w;
    float s2 = acc[i][0]*a2v.x + acc[i][1]*a2v.y + acc[i][2]*a2v.z + acc[i][3]*a2v.w;
#pragma unroll
    for (int off = 1; off < 16; off <<= 1) {
      s1 += __shfl_xor(s1, off);
      s2 += __shfl_xor(s2, off);
    }
    if (tc == 0) {
      int r = tr * 2 + i;
      siT[hh * NN + i0 + r] = s1 * LOG2E;
      float sjs = s2 * LOG2E;
      vT[hh * NN + i0 + r] = __builtin_amdgcn_exp2f(sjs);
      v2T[hh * NN + i0 + r] = __builtin_amdgcn_exp2f(0.2f * sjs);
      sjb[r] = sjs;
    }
    *(float4*)&hl[(tr * 2 + i) * 68 + tc * 4] =
        make_float4(acc[i][0], acc[i][1], acc[i][2], acc[i][3]);
  }
  __syncthreads();

  if (t < 32) {  // block-level sj max partial
    float v = sjb[t];
#pragma unroll
    for (int off = 1; off < 32; off <<= 1) v = fmaxf(v, __shfl_xor(v, off));
    if (t == 0) sjm[it * 4 + hh] = v;
  }

  // transpose -> hT[hh][d][i0..i0+31] bf16 (8 i's per thread)
  const int d = t & 63, g = t >> 6;
  bf16x8 h0;
#pragma unroll
  for (int ii = 0; ii < 8; ++ii) h0[ii] = (__bf16)hl[(g * 8 + ii) * 68 + d];
  *(bf16x8*)(hT + (size_t)(hh * 64 + d) * NN + i0 + g * 8) = h0;
}

// ---------------- Kernel B: masked softmax + PV (MFMA) ----------------
// grid (128 i-tiles of 32, S j-splits), 256 threads = 4 waves, wave w = head w.
__global__ __launch_bounds__(256, 4) void gat_attn(
    const int* __restrict__ adj, const __bf16* __restrict__ hT,
    const float* __restrict__ siT, const float* __restrict__ vT,
    const float* __restrict__ v2T, const float* __restrict__ sjm,
    float* __restrict__ accws, float* __restrict__ lws, int jper) {
  const int t = threadIdx.x;
  const int w = t >> 6, lane = t & 63, quad = lane >> 4, l16 = lane & 15;
  const int i0 = blockIdx.x * 32;
  const int s = blockIdx.y;
  const int jbeg = s * jper, jend = jbeg + jper;

  // global sj-max for this head (128 block-partials from gat_prep)
  float vv = fmaxf(sjm[lane * 4 + w], sjm[(lane + 64) * 4 + w]);
#pragma unroll
  for (int off = 1; off < 64; off <<= 1) vv = fmaxf(vv, __shfl_xor(vv, off));

  float u[2], u2[2];
#pragma unroll
  for (int mt = 0; mt < 2; ++mt) {
    float sis = siT[w * NN + i0 + mt * 16 + l16];
    float tt = sis + vv;
    float m = fmaxf(tt, 0.2f * tt);   // leaky monotone -> valid row-max upper bound
    u[mt] = __builtin_amdgcn_exp2f(sis - m);
    u2[mt] = __builtin_amdgcn_exp2f(0.2f * sis - m);
  }

  bf16x8 ones;
#pragma unroll
  for (int ii = 0; ii < 8; ++ii) ones[ii] = (__bf16)1.0f;

  floatx4 zv = {0.f, 0.f, 0.f, 0.f};
  floatx4 acc[2][4], lacc[2];
#pragma unroll
  for (int mt = 0; mt < 2; ++mt) {
    lacc[mt] = zv;
#pragma unroll
    for (int nt = 0; nt < 4; ++nt) acc[mt][nt] = zv;
  }

  const __bf16* hTw = hT + (size_t)w * 64 * NN;
  const float* vw = vT + w * NN;
  const float* v2w = v2T + w * NN;
  const int* adjr0 = adj + (size_t)(i0 + l16) * NN + quad * 8;
  const int* adjr1 = adj + (size_t)(i0 + 16 + l16) * NN + quad * 8;

#define LOADADJ(B, jj)              \
  {                                 \
    B[0] = *(const int4*)(adjr0 + (jj));     \
    B[1] = *(const int4*)(adjr0 + (jj) + 4); \
    B[2] = *(const int4*)(adjr1 + (jj));     \
    B[3] = *(const int4*)(adjr1 + (jj) + 4); \
  }

#define COMPUTE(B, j0)                                                         \
  {                                                                            \
    bf16x8 bfr[4];                                                             \
    _Pragma("unroll")                                                          \
    for (int nt = 0; nt < 4; ++nt)                                             \
      bfr[nt] = *(const bf16x8*)(hTw + (size_t)(nt * 16 + l16) * NN + (j0) + quad * 8); \
    float4 va = *(const float4*)(vw + (j0) + quad * 8);                        \
    float4 vb = *(const float4*)(vw + (j0) + quad * 8 + 4);                    \
    float4 wa = *(const float4*)(v2w + (j0) + quad * 8);                       \
    float4 wb = *(const float4*)(v2w + (j0) + quad * 8 + 4);                   \
    float vj[8] = {va.x, va.y, va.z, va.w, vb.x, vb.y, vb.z, vb.w};            \
    float v2j[8] = {wa.x, wa.y, wa.z, wa.w, wb.x, wb.y, wb.z, wb.w};           \
    _Pragma("unroll")                                                          \
    for (int mt = 0; mt < 2; ++mt) {                                           \
      int am[8] = {B[mt*2].x, B[mt*2].y, B[mt*2].z, B[mt*2].w,                 \
                   B[mt*2+1].x, B[mt*2+1].y, B[mt*2+1].z, B[mt*2+1].w};        \
      bf16x8 af;                                                               \
      _Pragma("unroll")                                                        \
      for (int jj = 0; jj < 8; ++jj) {                                         \
        float p = fmaxf(u[mt] * vj[jj], u2[mt] * v2j[jj]);                     \
        af[jj] = (__bf16)((am[jj] != 0) ? p : 0.f);                            \
      }                                                                        \
      _Pragma("unroll")                                                        \
      for (int nt = 0; nt < 4; ++nt)                                           \
        acc[mt][nt] = __builtin_amdgcn_mfma_f32_16x16x32_bf16(af, bfr[nt],     \
                                                              acc[mt][nt], 0, 0, 0); \
      lacc[mt] = __builtin_amdgcn_mfma_f32_16x16x32_bf16(af, ones,             \
                                                         lacc[mt], 0, 0, 0);  \
    }                                                                          \
  }

  int4 A0[4], A1[4];
  LOADADJ(A0, jbeg);
  for (int j0 = jbeg; j0 < jend; j0 += 64) {
    LOADADJ(A1, j0 + 32);
    COMPUTE(A0, j0);
    if (j0 + 64 < jend) LOADADJ(A0, j0 + 64);
    COMPUTE(A1, j0 + 32);
  }

  float* accs = accws + (size_t)s * NN * 256;
  float* lss = lws + (size_t)s * NN * 4;
  // C layout: row = mt*16 + quad*4 + reg, col = nt*16 + l16
#pragma unroll
  for (int mt = 0; mt < 2; ++mt)
#pragma unroll
    for (int reg = 0; reg < 4; ++reg) {
      int row = mt * 16 + quad * 4 + reg;
      float* op = accs + (size_t)(i0 + row) * 256 + w * 64;
#pragma unroll
      for (int nt = 0; nt < 4; ++nt)
        op[nt * 16 + l16] = acc[mt][nt][reg];
      if (l16 == 0) lss[(i0 + row) * 4 + w] = lacc[mt][reg];
    }
}

// ---------------- Kernel C: combine splits + normalize (float4) ----------------
__global__ __launch_bounds__(256) void gat_reduce(
    const float* __restrict__ accws, const float* __restrict__ lws,
    float* __restrict__ out, int S) {
  const int e4 = blockIdx.x * 256 + threadIdx.x;
  const int e = e4 * 4;                 // e = i*256 + h*64 + d
  const int i = e >> 8;
  const int h = (e & 255) >> 6;
  float4 a = make_float4(0.f, 0.f, 0.f, 0.f);
  float l = 0.f;
  for (int s = 0; s < S; ++s) {
    float4 v = *(const float4*)(accws + (size_t)s * (NN * 256) + e);
    a.x += v.x; a.y += v.y; a.z += v.z; a.w += v.w;
    l += lws[(size_t)s * (NN * 4) + i * 4 + h];
  }
  float inv = 1.0f / l;
  *(float4*)(out + e) = make_float4(a.x * inv, a.y * inv, a.z * inv, a.w * inv);
}

extern "C" void kernel_launch(void* const* d_in, const int* in_sizes, int n_in,
                              void* d_out, int out_size, void* d_ws, size_t ws_size,
                              hipStream_t stream) {
  const float* x  = (const float*)d_in[0];
  const int*   adj = (const int*)d_in[1];
  const float* W  = (const float*)d_in[2];
  const float* a1 = (const float*)d_in[3];
  const float* a2 = (const float*)d_in[4];
  float* out = (float*)d_out;
  char* ws = (char*)d_ws;

  // ws layout (bytes):
  //   hT   bf16 [4][64][4096]  @ 0        (2 MiB)
  //   siT  f32  [4][4096]      @ 2097152
  //   vT   f32  [4][4096]      @ 2162688
  //   v2T  f32  [4][4096]      @ 2228224
  //   sjm  f32  [128][4]       @ 2293760  (2 KiB)
  //   acc  f32  [S][4096][256] @ 2297856  (S * 4 MiB)
  //   l    f32  [S][4096][4]   after acc
  __bf16* hT  = (__bf16*)ws;
  float* siT  = (float*)(ws + 2097152);
  float* vT   = (float*)(ws + 2162688);
  float* v2T  = (float*)(ws + 2228224);
  float* sjm  = (float*)(ws + 2293760);
  float* accws = (float*)(ws + 2297856);

  size_t avail = ws_size > 2297856 ? ws_size - 2297856 : 0;
  int S = (int)(avail / 4259840);
  if (S >= 8) S = 8;
  else if (S >= 4) S = 4;
  else if (S >= 2) S = 2;
  else S = 1;
  float* lws = (float*)(ws + 2297856 + (size_t)S * 4194304);
  int jper = NN / S;

  gat_prep<<<dim3(128, 4), 256, 0, stream>>>(x, W, a1, a2, hT, siT, vT, v2T, sjm);
  gat_attn<<<dim3(128, S), 256, 0, stream>>>(adj, hT, siT, vT, v2T, sjm, accws, lws, jper);
  gat_reduce<<<1024, 256, 0, stream>>>(accws, lws, out, S);
}

// Round 3
// 180.186 us; speedup vs baseline: 1.1105x; 1.0946x over previous
//
#include <hip/hip_runtime.h>
#include <hip/hip_bf16.h>

// GAT: N=4096 nodes, IN_F=256, H=4 heads, D=64.
// K0 gat_pack : adj (64 MB int) -> adjb bitmask (2 MB), coalesced streaming.
// K1 gat_prep : h = x@W (fp32), siT = <h,a1>*log2e, vT = exp2(<h,a2>*log2e),
//               v2T = exp2(0.2*...), hT bf16 [H][D][N], per-block sj-max partials.
// K2 gat_attn : masked softmax + PV via mfma_16x16x32_bf16.
//               m_i = leaky(si + max_j sj) upper bound -> pure-sum softmax ->
//               waves split j; LDS combine; direct out write. Mask from L2-resident
//               bitmask; p_ij = max(u_i*v_j, u2_i*v2_j): no transcendentals in loop.

typedef __bf16 bf16x8 __attribute__((ext_vector_type(8)));
typedef float floatx4 __attribute__((ext_vector_type(4)));

#define LOG2E 1.4426950408889634f
#define NN 4096

// ---------------- Kernel 0: adj -> bitmask ----------------
// byte T: bit k = (adj[8T+k] != 0). 2048 blocks x 256 thr x 4 iters covers 2^21 bytes.
__global__ __launch_bounds__(256) void gat_pack(const int* __restrict__ adj,
                                                unsigned char* __restrict__ adjb) {
  int T = blockIdx.x * 256 + threadIdx.x;
  const int stride = 2048 * 256;
#pragma unroll
  for (int it = 0; it < 4; ++it, T += stride) {
    const int* p = adj + (size_t)T * 8;
    int4 a = *(const int4*)p;
    int4 b = *(const int4*)(p + 4);
    unsigned int m = 0;
    m |= (a.x != 0) ? 1u : 0u;
    m |= (a.y != 0) ? 2u : 0u;
    m |= (a.z != 0) ? 4u : 0u;
    m |= (a.w != 0) ? 8u : 0u;
    m |= (b.x != 0) ? 16u : 0u;
    m |= (b.y != 0) ? 32u : 0u;
    m |= (b.z != 0) ? 64u : 0u;
    m |= (b.w != 0) ? 128u : 0u;
    adjb[T] = (unsigned char)m;
  }
}

// ---------------- Kernel 1: h = x@W + per-row scalars + hT(bf16) ----------------
// grid (128 i-tiles of 32 rows, 4 heads), 256 threads.
__global__ __launch_bounds__(256) void gat_prep(
    const float* __restrict__ x, const float* __restrict__ W,
    const float* __restrict__ a1, const float* __restrict__ a2,
    __bf16* __restrict__ hT, float* __restrict__ siT, float* __restrict__ vT,
    float* __restrict__ v2T, float* __restrict__ sjm) {
  __shared__ float hl[32 * 68];
  __shared__ float sjb[32];
  const int t = threadIdx.x;
  const int it = blockIdx.x, hh = blockIdx.y;
  const int i0 = it * 32, c0 = hh * 64;
  const int tr = t >> 4, tc = t & 15;

  float acc[2][4] = {{0.f,0.f,0.f,0.f},{0.f,0.f,0.f,0.f}};
  const float* xr = x + (size_t)(i0 + tr * 2) * 256;
  const float* wp = W + c0 + tc * 4;
  for (int k = 0; k < 256; k += 4) {
    float4 xv0 = *(const float4*)(xr + k);
    float4 xv1 = *(const float4*)(xr + 256 + k);
    float xs[2][4] = {{xv0.x, xv0.y, xv0.z, xv0.w},
                      {xv1.x, xv1.y, xv1.z, xv1.w}};
#pragma unroll
    for (int kk = 0; kk < 4; ++kk) {
      float4 wv = *(const float4*)(wp + (size_t)(k + kk) * 256);
#pragma unroll
      for (int i = 0; i < 2; ++i) {
        acc[i][0] = fmaf(xs[i][kk], wv.x, acc[i][0]);
        acc[i][1] = fmaf(xs[i][kk], wv.y, acc[i][1]);
        acc[i][2] = fmaf(xs[i][kk], wv.z, acc[i][2]);
        acc[i][3] = fmaf(xs[i][kk], wv.w, acc[i][3]);
      }
    }
  }

  float4 a1v = *(const float4*)(a1 + tc * 4);
  float4 a2v = *(const float4*)(a2 + tc * 4);
#pragma unroll
  for (int i = 0; i < 2; ++i) {
    float s1 = acc[i][0]*a1v.x + acc[i][1]*a1v.y + acc[i][2]*a1v.z + acc[i][3]*a1v.w;
    float s2 = acc[i][0]*a2v.x + acc[i][1]*a2v.y + acc[i][2]*a2v.z + acc[i][3]*a2v.w;
#pragma unroll
    for (int off = 1; off < 16; off <<= 1) {
      s1 += __shfl_xor(s1, off);
      s2 += __shfl_xor(s2, off);
    }
    if (tc == 0) {
      int r = tr * 2 + i;
      siT[hh * NN + i0 + r] = s1 * LOG2E;
      float sjs = s2 * LOG2E;
      vT[hh * NN + i0 + r] = __builtin_amdgcn_exp2f(sjs);
      v2T[hh * NN + i0 + r] = __builtin_amdgcn_exp2f(0.2f * sjs);
      sjb[r] = sjs;
    }
    *(float4*)&hl[(tr * 2 + i) * 68 + tc * 4] =
        make_float4(acc[i][0], acc[i][1], acc[i][2], acc[i][3]);
  }
  __syncthreads();

  if (t < 32) {
    float v = sjb[t];
#pragma unroll
    for (int off = 1; off < 32; off <<= 1) v = fmaxf(v, __shfl_xor(v, off));
    if (t == 0) sjm[it * 4 + hh] = v;
  }

  const int d = t & 63, g = t >> 6;
  bf16x8 h0;
#pragma unroll
  for (int ii = 0; ii < 8; ++ii) h0[ii] = (__bf16)hl[(g * 8 + ii) * 68 + d];
  *(bf16x8*)(hT + (size_t)(hh * 64 + d) * NN + i0 + g * 8) = h0;
}

// ---------------- Kernel 2: masked softmax + PV (MFMA), direct out ----------------
// grid (128 i-tiles of 32, 4 heads), 256 threads = 4 waves; wave w = j-range w.
__global__ __launch_bounds__(256, 2) void gat_attn(
    const unsigned int* __restrict__ adjw, const __bf16* __restrict__ hT,
    const float* __restrict__ siT, const float* __restrict__ vT,
    const float* __restrict__ v2T, const float* __restrict__ sjm,
    float* __restrict__ out) {
  __shared__ float accs[4][32][68];
  __shared__ float lsum[4][32];
  const int t = threadIdx.x;
  const int w = t >> 6, lane = t & 63, quad = lane >> 4, l16 = lane & 15;
  const int i0 = blockIdx.x * 32;
  const int hh = blockIdx.y;

  // global sj-max for this head
  float vv = fmaxf(sjm[lane * 4 + hh], sjm[(lane + 64) * 4 + hh]);
#pragma unroll
  for (int off = 1; off < 64; off <<= 1) vv = fmaxf(vv, __shfl_xor(vv, off));

  float u[2], u2[2];
#pragma unroll
  for (int mt = 0; mt < 2; ++mt) {
    float sis = siT[hh * NN + i0 + mt * 16 + l16];
    float tt = sis + vv;
    float m = fmaxf(tt, 0.2f * tt);   // leaky monotone -> valid row-max upper bound
    u[mt] = __builtin_amdgcn_exp2f(sis - m);
    u2[mt] = __builtin_amdgcn_exp2f(0.2f * sis - m);
  }

  bf16x8 ones;
#pragma unroll
  for (int ii = 0; ii < 8; ++ii) ones[ii] = (__bf16)1.0f;

  floatx4 zv = {0.f, 0.f, 0.f, 0.f};
  floatx4 acc[2][4], lacc[2];
#pragma unroll
  for (int mt = 0; mt < 2; ++mt) {
    lacc[mt] = zv;
#pragma unroll
    for (int nt = 0; nt < 4; ++nt) acc[mt][nt] = zv;
  }

  const __bf16* hTw = hT + (size_t)hh * 64 * NN;
  const float* vw = vT + hh * NN;
  const float* v2w = v2T + hh * NN;
  const unsigned int* ar0 = adjw + (size_t)(i0 + l16) * 128;
  const unsigned int* ar1 = adjw + (size_t)(i0 + 16 + l16) * 128;

  const int jbeg = w * (NN / 4), jend = jbeg + NN / 4;

  // prefetch registers for step j0, computed while staging j0+32
  unsigned int w0c, w1c, w0n, w1n;
  bf16x8 bfc[4], bfn[4];
  float4 vac, vbc, v2ac, v2bc, van, vbn, v2an, v2bn;

#define STAGE(J, W0, W1, BF, VA, VB, V2A, V2B)                                  \
  {                                                                             \
    W0 = ar0[(J) >> 5];                                                         \
    W1 = ar1[(J) >> 5];                                                         \
    _Pragma("unroll")                                                           \
    for (int nt = 0; nt < 4; ++nt)                                              \
      BF[nt] = *(const bf16x8*)(hTw + (size_t)(nt * 16 + l16) * NN + (J) + quad * 8); \
    VA = *(const float4*)(vw + (J) + quad * 8);                                 \
    VB = *(const float4*)(vw + (J) + quad * 8 + 4);                             \
    V2A = *(const float4*)(v2w + (J) + quad * 8);                               \
    V2B = *(const float4*)(v2w + (J) + quad * 8 + 4);                           \
  }

#define COMPUTE(W0, W1, BF, VA, VB, V2A, V2B)                                   \
  {                                                                             \
    float vj[8] = {VA.x, VA.y, VA.z, VA.w, VB.x, VB.y, VB.z, VB.w};             \
    float v2j[8] = {V2A.x, V2A.y, V2A.z, V2A.w, V2B.x, V2B.y, V2B.z, V2B.w};    \
    _Pragma("unroll")                                                           \
    for (int mt = 0; mt < 2; ++mt) {                                            \
      unsigned int m8 = ((mt ? W1 : W0) >> (quad * 8));                         \
      bf16x8 af;                                                                \
      _Pragma("unroll")                                                         \
      for (int jj = 0; jj < 8; ++jj) {                                          \
        float p = fmaxf(u[mt] * vj[jj], u2[mt] * v2j[jj]);                      \
        af[jj] = ((m8 >> jj) & 1u) ? (__bf16)p : (__bf16)0.f;                   \
      }                                                                         \
      _Pragma("unroll")                                                         \
      for (int nt = 0; nt < 4; ++nt)                                            \
        acc[mt][nt] = __builtin_amdgcn_mfma_f32_16x16x32_bf16(af, BF[nt],       \
                                                              acc[mt][nt], 0, 0, 0); \
      lacc[mt] = __builtin_amdgcn_mfma_f32_16x16x32_bf16(af, ones,              \
                                                         lacc[mt], 0, 0, 0);   \
    }                                                                           \
  }

  STAGE(jbeg, w0c, w1c, bfc, vac, vbc, v2ac, v2bc);
  for (int j0 = jbeg; j0 < jend; j0 += 64) {
    STAGE(j0 + 32, w0n, w1n, bfn, van, vbn, v2an, v2bn);
    COMPUTE(w0c, w1c, bfc, vac, vbc, v2ac, v2bc);
    if (j0 + 64 < jend) STAGE(j0 + 64, w0c, w1c, bfc, vac, vbc, v2ac, v2bc);
    COMPUTE(w0n, w1n, bfn, van, vbn, v2an, v2bn);
  }

  // epilogue: park partials in LDS, combine across the 4 j-split waves
  // C layout: row = mt*16 + quad*4 + reg, col = nt*16 + l16
#pragma unroll
  for (int mt = 0; mt < 2; ++mt)
#pragma unroll
    for (int reg = 0; reg < 4; ++reg) {
      int row = mt * 16 + quad * 4 + reg;
#pragma unroll
      for (int nt = 0; nt < 4; ++nt)
        accs[w][row][nt * 16 + l16] = acc[mt][nt][reg];
      if (l16 == 0) lsum[w][row] = lacc[mt][reg];
    }
  __syncthreads();

  const int r = t >> 3, c = (t & 7) * 8;
  float l = lsum[0][r] + lsum[1][r] + lsum[2][r] + lsum[3][r];
  float inv = 1.0f / l;
  float o[8];
#pragma unroll
  for (int k = 0; k < 8; ++k)
    o[k] = (accs[0][r][c + k] + accs[1][r][c + k] +
            accs[2][r][c + k] + accs[3][r][c + k]) * inv;
  float* op = out + (size_t)(i0 + r) * 256 + hh * 64 + c;
  *(float4*)op = make_float4(o[0], o[1], o[2], o[3]);
  *(float4*)(op + 4) = make_float4(o[4], o[5], o[6], o[7]);
}

extern "C" void kernel_launch(void* const* d_in, const int* in_sizes, int n_in,
                              void* d_out, int out_size, void* d_ws, size_t ws_size,
                              hipStream_t stream) {
  const float* x  = (const float*)d_in[0];
  const int*   adj = (const int*)d_in[1];
  const float* W  = (const float*)d_in[2];
  const float* a1 = (const float*)d_in[3];
  const float* a2 = (const float*)d_in[4];
  float* out = (float*)d_out;
  char* ws = (char*)d_ws;

  // ws layout (bytes):
  //   hT   bf16 [4][64][4096]  @ 0        (2 MiB)
  //   siT  f32  [4][4096]      @ 2097152
  //   vT   f32  [4][4096]      @ 2162688
  //   v2T  f32  [4][4096]      @ 2228224
  //   sjm  f32  [128][4]       @ 2293760  (2 KiB)
  //   adjb u8   [4096][512]    @ 2295808  (2 MiB bitmask)
  __bf16* hT  = (__bf16*)ws;
  float* siT  = (float*)(ws + 2097152);
  float* vT   = (float*)(ws + 2162688);
  float* v2T  = (float*)(ws + 2228224);
  float* sjm  = (float*)(ws + 2293760);
  unsigned char* adjb = (unsigned char*)(ws + 2295808);

  gat_pack<<<2048, 256, 0, stream>>>(adj, adjb);
  gat_prep<<<dim3(128, 4), 256, 0, stream>>>(x, W, a1, a2, hT, siT, vT, v2T, sjm);
  gat_attn<<<dim3(128, 4), 256, 0, stream>>>((const unsigned int*)adjb, hT, siT, vT,
                                             v2T, sjm, out);
}